// Round 2
// baseline (195.717 us; speedup 1.0000x reference)
//
#include <hip/hip_runtime.h>
#include <hip/hip_bf16.h>

typedef __attribute__((ext_vector_type(8))) short bf16x8;
typedef __attribute__((ext_vector_type(4))) float f32x4;

#define NB 16
#define C 256
#define HH 56
#define WW 56
#define HW 3136
#define CHW 802816
#define NPIX 50176
#define PH 58
#define PW 58
#define KTOT 2304
#define PPI 3364      // 58*58 padded pixels per image
#define NPIXP 53824   // 16*3364 total padded pixels

#define GLL(g, l) __builtin_amdgcn_global_load_lds( \
    (const __attribute__((address_space(1))) void*)(g), \
    (__attribute__((address_space(3))) void*)(l), 16, 0, 0)

// ---------------- kernel 1: BN stats (fp64 accum, float4 loads, 1024 thr) ----------------
__global__ __launch_bounds__(1024) void stats_kernel(const float* __restrict__ x,
                             const float* __restrict__ gamma, double* __restrict__ stats) {
  int c = blockIdx.x, tid = threadIdx.x;
  double s = 0.0, s2 = 0.0;
  const float* xc = x + (size_t)c * HW;
  for (int k = tid; k < NB * (HW / 4); k += 1024) {   // 12544 float4s
    int n = k / (HW / 4), i = k - n * (HW / 4);
    float4 v = *(const float4*)(xc + (size_t)n * CHW + i * 4);
    double a = v.x, b = v.y, cc = v.z, d = v.w;
    s  += (a + b) + (cc + d);
    s2 += (a * a + b * b) + (cc * cc + d * d);
  }
  __shared__ double rs[1024], rq[1024];
  rs[tid] = s; rq[tid] = s2; __syncthreads();
  for (int o = 512; o > 0; o >>= 1) {
    if (tid < o) { rs[tid] += rs[tid + o]; rq[tid] += rq[tid + o]; }
    __syncthreads();
  }
  if (tid == 0) {
    double mean = rs[0] / (double)NPIX;
    double var = rq[0] / (double)NPIX - mean * mean;
    stats[c] = mean;
    stats[C + c] = (double)gamma[c] / sqrt(var + 1e-4);
  }
}

// ------- kernel 2: ternarize -> padded NHWC (channel-permuted) bf16 Tp + c_sum -------
// channel permutation: slot p = (c&31)*8 + (c>>5)  <->  c = (p&7)*32 + (p>>3)
__global__ __launch_bounds__(256) void ternarize_kernel(const float* __restrict__ x,
                                 const float* __restrict__ beta,
                                 const double* __restrict__ stats,
                                 unsigned short* __restrict__ Tp, float* __restrict__ csum) {
  int bid = blockIdx.x, tid = threadIdx.x;
  int n = bid / HH, h = bid - n * HH;
  __shared__ float xs[256][57];   // stride 57: transposed reads conflict-free
  const float* xb = x + (size_t)n * CHW + h * WW;
#pragma unroll
  for (int j = 0; j < 14; ++j) {
    int idx = j * 256 + tid;
    int c = idx / 14, q = idx - c * 14;
    float4 v = *(const float4*)(xb + (size_t)c * HW + q * 4);
    float* row = &xs[c][q * 4];
    row[0] = v.x; row[1] = v.y; row[2] = v.z; row[3] = v.w;
  }
  int c8 = tid & 31;
  double mu[8], sc[8], bt[8];
#pragma unroll
  for (int e = 0; e < 8; ++e) {
    int c = c8 + 32 * e;
    mu[e] = stats[c]; sc[e] = stats[C + c]; bt[e] = (double)beta[c];
  }
  __syncthreads();
  unsigned short* tb = Tp + ((size_t)(n * PH + h + 1) * PW + 1) * C;
  float* cs = csum + (size_t)(n * PH + h + 1) * PW + 1;
#pragma unroll
  for (int p = 0; p < 7; ++p) {
    int idx = p * 256 + tid;
    int w = idx >> 5;
    unsigned bits[4];
    float msum = 0.f;
#pragma unroll
    for (int e2 = 0; e2 < 4; ++e2) {
      unsigned lo, hi;
      {
        double xn = ((double)xs[c8 + 64 * e2][w] - mu[2 * e2]) * sc[2 * e2] + bt[2 * e2];
        lo = (xn > 0.0) ? 0x3F80u : 0xBF80u;
        msum += (float)fmin(fabs(xn), 1.0);
      }
      {
        double xn = ((double)xs[c8 + 64 * e2 + 32][w] - mu[2 * e2 + 1]) * sc[2 * e2 + 1] + bt[2 * e2 + 1];
        hi = (xn > 0.0) ? 0x3F80u : 0xBF80u;
        msum += (float)fmin(fabs(xn), 1.0);
      }
      bits[e2] = lo | (hi << 16);
    }
    msum += __shfl_xor(msum, 1); msum += __shfl_xor(msum, 2);
    msum += __shfl_xor(msum, 4); msum += __shfl_xor(msum, 8);
    msum += __shfl_xor(msum, 16);
    uint4 v4; v4.x = bits[0]; v4.y = bits[1]; v4.z = bits[2]; v4.w = bits[3];
    *(uint4*)(tb + (size_t)w * C + c8 * 8) = v4;
    if (c8 == 0) cs[w] = msum;
  }
}

// ------- kernel 2b (fused prep): wprep (coalesced-read version) + Tp border zero + csum zero -------
__global__ void prep_kernel(const float* __restrict__ cw, unsigned short* __restrict__ Wp,
                            unsigned short* __restrict__ Tp, float* __restrict__ csum) {
  int b = blockIdx.x, tid = threadIdx.x;
  if (b < 256) {
    // weights OIHW -> [co][tap][perm(c)] bf16 (RNE).
    int co = b;
    const float* src = cw + (size_t)co * KTOT;
    unsigned short* dst = Wp + (size_t)co * KTOT;
    float v[9];
#pragma unroll
    for (int t9 = 0; t9 < 9; ++t9) v[t9] = src[tid * 9 + t9];
    int p = (tid & 31) * 8 + (tid >> 5);       // perm slot for channel c=tid
#pragma unroll
    for (int t9 = 0; t9 < 9; ++t9) {
      unsigned u = __builtin_bit_cast(unsigned, v[t9]);
      unsigned lsb = (u >> 16) & 1u;
      u += 0x7FFFu + lsb;
      dst[t9 * 256 + p] = (unsigned short)(u >> 16);
    }
  } else if (b < 712) {
    int g = (b - 256) * 256 + tid;  // 456*256 = 116736 = 16*228*32 exactly
    int n = g / 7296; int r = g - n * 7296;
    int pix = r >> 5, c8 = r & 31;
    int h, w;
    if (pix < 58)      { h = 0;  w = pix; }
    else if (pix < 116){ h = 57; w = pix - 58; }
    else { int rem = pix - 116; h = 1 + (rem >> 1); w = (rem & 1) ? 57 : 0; }
    uint4 z = {0u, 0u, 0u, 0u};
    *(uint4*)(Tp + (size_t)((n * PH + h) * PW + w) * C + c8 * 8) = z;
  } else {
    int i = (b - 712) * 256 + tid;
    if (i < NPIXP) csum[i] = 0.f;
  }
}

// ------- kernel 5: double-buffered union-window implicit-GEMM ternary conv -------
// Block: 512 thr (8 waves), tile M=64 co x N=512 padded pixels, K-chunks of 32 (8 stages).
// LDS: A dbuf 2x36864 + B dbuf 2x40960 = 155,648 B -> 1 block/CU, 8 waves (2/SIMD).
// Per stage: ONE __syncthreads (its vmcnt(0) drain is free: the drained loads had the
// whole previous compute phase ~5600 cyc in flight), then issue next stage's GLLs into
// the other buffer, then 9 taps x 16 MFMA per wave under s_setprio(1). Loads fully
// overlap compute; per-CU stage is MFMA-bound (5587 cyc MFMA vs 1390 cyc GLL feed).
// betamap is fused into the epilogue (csum 9-tap box sum, L2-resident).
__global__ __launch_bounds__(512, 2) void conv_kernel(const unsigned short* __restrict__ Wp,
    const unsigned short* __restrict__ Tp, const float* __restrict__ convb,
    const float* __restrict__ csum, const float* __restrict__ betab,
    float* __restrict__ out) {
  int bid = blockIdx.x;
  int ptg = bid >> 5, xcd = bid & 7, ct = (bid >> 3) & 3;
  int pt = ptg * 8 + xcd;                    // pixel tile (same-XCD blocks share it)
  if (pt >= 106) return;
  int tid = threadIdx.x;
  int co0 = ct * 64;

  __shared__ __align__(16) unsigned short As[2][18432];   // 2 x 36864 B
  __shared__ __align__(16) unsigned short Bs[2][20480];   // 2 x 40960 B

  // ---- A staging plan: 4.5 GLL rounds (rounds 0-3 full, round 4 tid<256)
  // lin -> [tap9][co64][physseg4]; XOR-on-global-segment keeps ds_read conflict-free.
  int aofs[5];
#pragma unroll
  for (int r = 0; r < 5; ++r) {
    int lin = r * 512 + tid;
    int co = (lin >> 2) & 63, tap = lin >> 8, pseg = lin & 3;
    int lseg = pseg ^ ((co >> 1) & 3);
    aofs[r] = (co0 + co) * KTOT + tap * 256 + lseg * 8;   // + c0 (tap>8 rows never issued)
  }
  // ---- B staging plan: 5 GLL rounds over union window [pt*512-59, +640)
  int wstart = pt * 512 - 59;
  int bofs[5];
#pragma unroll
  for (int r = 0; r < 5; ++r) {
    int lin = r * 512 + tid;
    int bpix = lin >> 2, pseg = lin & 3;
    int lseg = pseg ^ ((bpix >> 1) & 3);
    int q = wstart + bpix;
    q = q < 0 ? 0 : (q >= NPIXP ? NPIXP - 1 : q);   // clamped rows feed only skipped outputs
    bofs[r] = q * C + lseg * 8;
  }

  int lane = tid & 63, wid = tid >> 6;
  int quad = lane >> 4, row16 = lane & 15;
  int aFoff = row16 * 32 + (quad ^ ((row16 >> 1) & 3)) * 8;  // + tap*2048 + mi*512
  int pixb = wid * 64 + row16;                 // staged row = pixb + ni*16 + kh*58 + kw

  f32x4 acc[4][4];
#pragma unroll
  for (int mi = 0; mi < 4; ++mi)
#pragma unroll
    for (int ni = 0; ni < 4; ++ni)
      acc[mi][ni] = (f32x4){0.f, 0.f, 0.f, 0.f};

  // prologue: stage chunk 0 into buffer 0
#pragma unroll
  for (int r = 0; r < 4; ++r) GLL(Wp + aofs[r], &As[0][(r * 512 + tid) * 8]);
  if (tid < 256)               GLL(Wp + aofs[4], &As[0][(2048 + tid) * 8]);
#pragma unroll
  for (int r = 0; r < 5; ++r) GLL(Tp + bofs[r], &Bs[0][(r * 512 + tid) * 8]);

  for (int s = 0; s < 8; ++s) {
    int cur = s & 1;
    __syncthreads();            // drains chunk-s loads; all waves done reading buf cur^1
    if (s < 7) {
      int c0n = (s + 1) * 32;
#pragma unroll
      for (int r = 0; r < 4; ++r) GLL(Wp + aofs[r] + c0n, &As[cur ^ 1][(r * 512 + tid) * 8]);
      if (tid < 256)               GLL(Wp + aofs[4] + c0n, &As[cur ^ 1][(2048 + tid) * 8]);
#pragma unroll
      for (int r = 0; r < 5; ++r) GLL(Tp + bofs[r] + c0n, &Bs[cur ^ 1][(r * 512 + tid) * 8]);
    }
    const unsigned short* aB = &As[cur][0];
    const unsigned short* bB = &Bs[cur][0];
    __builtin_amdgcn_s_setprio(1);
#pragma unroll
    for (int kh = 0; kh < 3; ++kh) {
#pragma unroll
      for (int kw = 0; kw < 3; ++kw) {
        int tap = kh * 3 + kw;
        bf16x8 a[4], b[4];
#pragma unroll
        for (int mi = 0; mi < 4; ++mi)
          a[mi] = *(const bf16x8*)(aB + tap * 2048 + mi * 512 + aFoff);
#pragma unroll
        for (int ni = 0; ni < 4; ++ni) {
          int pix = pixb + ni * 16 + kh * 58 + kw;
          b[ni] = *(const bf16x8*)(bB + pix * 32 + ((quad ^ ((pix >> 1) & 3)) * 8));
        }
#pragma unroll
        for (int mi = 0; mi < 4; ++mi)
#pragma unroll
          for (int ni = 0; ni < 4; ++ni)
            acc[mi][ni] = __builtin_amdgcn_mfma_f32_16x16x32_bf16(a[mi], b[ni], acc[mi][ni], 0, 0, 0);
      }
    }
    __builtin_amdgcn_s_setprio(0);
  }

  // epilogue: out = (acc + conv_b) * beta_map(inline) ; skip padded-border outputs
  float bb = betab[0];
#pragma unroll
  for (int ni = 0; ni < 4; ++ni) {
    int pp = pt * 512 + wid * 64 + ni * 16 + row16;
    if (pp >= NPIXP) continue;
    int n = pp / PPI; int r2 = pp - n * PPI;
    int ph = r2 / PW;  int pw = r2 - ph * PW;
    if (ph < 1 || ph > 56 || pw < 1 || pw > 56) continue;
    const float* cp = csum + (size_t)(n * PH + ph - 1) * PW + (pw - 1);
    float s9 = 0.f;
#pragma unroll
    for (int i = 0; i < 3; ++i)
#pragma unroll
      for (int j = 0; j < 3; ++j) s9 += cp[i * PW + j];
    int rows = 3 - (ph == 1) - (ph == 56);
    int cols = 3 - (pw == 1) - (pw == 56);
    float bm = (s9 + bb) / (256.0f * (float)(rows * cols) + bb);
    int pix = (ph - 1) * WW + (pw - 1);
    float* ob = out + (size_t)n * CHW + pix;
#pragma unroll
    for (int mi = 0; mi < 4; ++mi) {
      int co = co0 + mi * 16 + quad * 4;
#pragma unroll
      for (int rg = 0; rg < 4; ++rg) {
        ob[(size_t)(co + rg) * HW] = (acc[mi][ni][rg] + convb[co + rg]) * bm;
      }
    }
  }
}

extern "C" void kernel_launch(void* const* d_in, const int* in_sizes, int n_in,
                              void* d_out, int out_size, void* d_ws, size_t ws_size,
                              hipStream_t stream) {
  const float* x     = (const float*)d_in[0];
  const float* gamma = (const float*)d_in[1];
  const float* beta  = (const float*)d_in[2];
  const float* convw = (const float*)d_in[3];
  const float* convb = (const float*)d_in[4];
  const float* betab = (const float*)d_in[5];
  float* out = (float*)d_out;

  char* ws = (char*)d_ws;
  unsigned short* Tp   = (unsigned short*)(ws);                 // 16*58*58*256*2 = 27,557,888
  unsigned short* Wp   = (unsigned short*)(ws + 27557888);      // 256*2304*2     =  1,179,648
  float*          csum = (float*)(ws + 28737536);               // 16*58*58*4     =    215,296
  double*         stats= (double*)(ws + 29153536);              // 512*8          =      4,096

  prep_kernel<<<923, 256, 0, stream>>>(convw, Wp, Tp, csum);
  stats_kernel<<<256, 1024, 0, stream>>>(x, gamma, stats);
  ternarize_kernel<<<896, 256, 0, stream>>>(x, beta, stats, Tp, csum);
  conv_kernel<<<448, 512, 0, stream>>>(Wp, Tp, convb, csum, betab, out);
}